// Round 2
// baseline (269.173 us; speedup 1.0000x reference)
//
#include <hip/hip_runtime.h>
#include <hip/hip_bf16.h>
#include <math.h>

// CRF loss on MI355X — fused, occupancy-doubled version + bf16 chunk stage.
//   k_prep:    W fp32->bf16 (pad 52->64), expT = exp(Tpad) bf16 [64][64], zero gold
//   k_scan:    per-wave fused: emit GEMM (16x64x1024 bf16 MFMA, 4-deep A prefetch)
//              -> bf16 emit tile in wave-private LDS -> gold partial (atomic)
//              -> 16-step transfer-matrix product (bf16 MFMA, no barriers)
//              -> dump P as bf16 (exact: pt is already bf16) — halves stage traffic
//   k_combine: 32 sequential 64x64 matvecs per batch, 4-deep register prefetch
//              (loads issued 3 iterations ahead -> HBM/L3 latency fully hidden)
//              + last-tag term + atomic mean
//
// Scan math: P <- diag(exp(emit_t - (7+r)ln2)) * exp(Tpad) * P; exp(Tpad) is a
// constant MFMA A-operand (loaded from precomputed expT); fixed 2^-7/step shift
// folded into the exp arg + exact power-of-2 rescale at t==7; integer exponent
// accumulated. Padding: Tpad[i][j>=52]=NEG (exp->0), Tpad[i>=52][j<52]=0
// (finite pad rows, excluded at the end by exp(TSTOP[j>=52])=0).
// All LDS is wave-private, accessed in program order -> NO __syncthreads in k_scan.
// Occupancy: 2048 wave-chunks / 512 blocks / 2 blocks/CU = 8 waves/CU.

#define NEGV   (-100000000.0f)
#define BB     64
#define TT     512
#define FF     1024
#define HH     52
#define HP     64
#define S_START 50
#define S_STOP  51
#define NCH    32            // chunks per batch
#define CLEN   (TT / NCH)    // 16 steps per chunk

typedef __bf16 bf16x8 __attribute__((ext_vector_type(8)));
typedef __bf16 bf16x4 __attribute__((ext_vector_type(4)));
typedef float  f32x4  __attribute__((ext_vector_type(4)));

// ---------------- ws layout (bytes) ----------------
#define WS_CHUNK  0u           // bf16 [2048][4096]               16,777,216
#define WS_WBF    33554432u    // bf16 [HP][FF]                      131,072
#define WS_EXPT   33685504u    // bf16 [64][64]                        8,192
#define WS_GOLD   33693696u    // fp32 [BB]
#define WS_CEXP   33693952u    // fp32 [2048]

// ---- W fp32 -> bf16 (pad rows 52..63 = 0); block 0: gold=0 and expT ----
__global__ __launch_bounds__(256) void k_prep(const float* __restrict__ W,
                                              const float* __restrict__ trans,
                                              __bf16* __restrict__ wbf,
                                              __bf16* __restrict__ expT,
                                              float* __restrict__ gold) {
  int n = blockIdx.x;  // 0..63
  if (n == 0) {
    if (threadIdx.x < BB) gold[threadIdx.x] = 0.0f;
    for (int idx = threadIdx.x; idx < 4096; idx += 256) {
      int m = idx >> 6, k = idx & 63;
      float tv = (k >= HH) ? NEGV : ((m >= HH) ? 0.0f : trans[m * HH + k]);
      expT[idx] = (__bf16)__expf(tv);
    }
  }
  for (int k = threadIdx.x; k < FF; k += 256) {
    float v = (n < HH) ? W[n * FF + k] : 0.0f;
    wbf[n * FF + k] = (__bf16)v;
  }
}

// ---- fused GEMM + gold partial + scan: 512 blocks x 4 waves = 2048 chunks ----
__global__ __launch_bounds__(256, 2) void k_scan(const float* __restrict__ feat,
                                                 const __bf16* __restrict__ wbf,
                                                 const __bf16* __restrict__ expT,
                                                 const float* __restrict__ bias,
                                                 const float* __restrict__ trans,
                                                 const float* __restrict__ masks,
                                                 const int* __restrict__ tags,
                                                 __bf16* __restrict__ chunks,
                                                 float* __restrict__ cexp,
                                                 float* __restrict__ gold) {
  const int tid = threadIdx.x;
  const int wv = tid >> 6;
  const int l  = tid & 63;
  const int lm = l & 15;
  const int q  = l >> 4;
  const int chunk = blockIdx.x * 4 + wv;   // 0..2047
  const int b = chunk >> 5, c = chunk & 31;

  __shared__ __align__(16) __bf16 PTall[4][64 * 72];   // 36,864 B
  __shared__ __align__(16) __bf16 Eall[4][CLEN * 64];  //  8,192 B
  __bf16* pt = PTall[wv];
  __bf16* el = Eall[wv];

  // ================= emit GEMM: M=16 (t), N=64 (state), K=1024 =================
  const float* fbase = feat + ((size_t)(b * TT + c * CLEN)) * FF;
  const float* arow  = fbase + (size_t)lm * FF + q * 8;

  // A prefetch, 4 k-chunks deep (32 B/lane per k-chunk)
  f32x4 apre[4][2];
#pragma unroll
  for (int s = 0; s < 4; ++s)
#pragma unroll
    for (int h = 0; h < 2; ++h)
      apre[s][h] = *(const f32x4*)(arow + s * 32 + h * 4);

  bf16x8 bcur[4];
#pragma unroll
  for (int nt = 0; nt < 4; ++nt)
    bcur[nt] = *(const bf16x8*)(wbf + (size_t)(nt * 16 + lm) * FF + q * 8);

  f32x4 acc[4] = {};

#pragma unroll
  for (int kt = 0; kt < 32; ++kt) {
    const int st = kt & 3;
    bf16x8 af;
#pragma unroll
    for (int j = 0; j < 4; ++j) {
      af[j]     = (__bf16)apre[st][0][j];
      af[4 + j] = (__bf16)apre[st][1][j];
    }
    if (kt + 4 < 32) {
#pragma unroll
      for (int h = 0; h < 2; ++h)
        apre[st][h] = *(const f32x4*)(arow + (kt + 4) * 32 + h * 4);
    }
    bf16x8 bnx[4];
    if (kt + 1 < 32) {
#pragma unroll
      for (int nt = 0; nt < 4; ++nt)
        bnx[nt] = *(const bf16x8*)(wbf + (size_t)(nt * 16 + lm) * FF + (kt + 1) * 32 + q * 8);
    }
#pragma unroll
    for (int nt = 0; nt < 4; ++nt)
      acc[nt] = __builtin_amdgcn_mfma_f32_16x16x32_bf16(af, bcur[nt], acc[nt], 0, 0, 0);
    if (kt + 1 < 32) {
#pragma unroll
      for (int nt = 0; nt < 4; ++nt) bcur[nt] = bnx[nt];
    }
  }

  // epilogue -> LDS emit tile (bf16): el[t*64 + state]; D: row=q*4+rr, col=lm
#pragma unroll
  for (int nt = 0; nt < 4; ++nt) {
    int n = nt * 16 + lm;
    float bn = (n < HH) ? bias[n] : 0.0f;
#pragma unroll
    for (int rr = 0; rr < 4; ++rr)
      el[(q * 4 + rr) * 64 + n] = (__bf16)(acc[nt][rr] + bn);
  }

  // ================= gold partial for this chunk =================
  float mreg = (l < CLEN) ? masks[b * TT + c * CLEN + l] : 1.0f;
  int cur = (l < CLEN) ? tags[b * TT + c * CLEN + l] : 0;
  int prev = __shfl_up(cur, 1);
  if (l == 0) prev = (c == 0) ? S_START : tags[b * TT + c * CLEN - 1];
  float gp = 0.0f;
  if (l < CLEN) {
    float e  = (float)el[l * 64 + cur];
    float tr = trans[cur * HH + prev];
    gp = (e + tr) * mreg;
  }
#pragma unroll
  for (int d = 1; d < 64; d <<= 1) gp += __shfl_xor(gp, d);
  if (l == 0) atomicAdd(&gold[b], gp);

  // ================= scan =================
  // constant A = exp(Tpad) from precomputed table: 8 vector loads
  bf16x8 afrag[4][2];
#pragma unroll
  for (int mt = 0; mt < 4; ++mt)
#pragma unroll
    for (int kk = 0; kk < 2; ++kk)
      afrag[mt][kk] = *(const bf16x8*)&expT[(mt * 16 + lm) * 64 + kk * 32 + q * 8];

  // P = I (wave-private; in-order LDS -> no barriers)
  for (int idx = l; idx < 4096; idx += 64) {
    int n = idx >> 6, mm = idx & 63;
    pt[n * 72 + mm] = (__bf16)((n == mm) ? 1.0f : 0.0f);
  }

  int eacc = 0, rpend = 0;
  const float LOG2E = 1.4426950408889634f;

  for (int t = 0; t < CLEN; ++t) {
    float mcur = __shfl(mreg, t);             // wave-uniform
    if (mcur != 0.0f) {
      float sh = (float)(7 + rpend);
      eacc += 7 + rpend;
      rpend = 0;
      float s[4][4];
#pragma unroll
      for (int mt = 0; mt < 4; ++mt) {
        bf16x4 em4 = *(const bf16x4*)&el[t * 64 + mt * 16 + q * 4];
#pragma unroll
        for (int rr = 0; rr < 4; ++rr)
          s[mt][rr] = __builtin_amdgcn_exp2f(fmaf((float)em4[rr], LOG2E, -sh));
      }

      // ALL reads before ALL writes (in-order LDS per wave)
      bf16x8 bfr[2][4];
#pragma unroll
      for (int kk = 0; kk < 2; ++kk)
#pragma unroll
        for (int nt = 0; nt < 4; ++nt)
          bfr[kk][nt] = *(const bf16x8*)&pt[(nt * 16 + lm) * 72 + kk * 32 + q * 8];

      const bool trk = ((t & 7) == 7) && (t != CLEN - 1);
      float lmax = 0.0f;
      f32x4 zero = {};
#pragma unroll
      for (int mt = 0; mt < 4; ++mt) {
#pragma unroll
        for (int nt = 0; nt < 4; ++nt) {
          f32x4 a = __builtin_amdgcn_mfma_f32_16x16x32_bf16(afrag[mt][0], bfr[0][nt], zero, 0, 0, 0);
          a = __builtin_amdgcn_mfma_f32_16x16x32_bf16(afrag[mt][1], bfr[1][nt], a, 0, 0, 0);
          bf16x4 w4;
#pragma unroll
          for (int rr = 0; rr < 4; ++rr) {
            float v = a[rr] * s[mt][rr];
            if (trk) lmax = fmaxf(lmax, v);
            w4[rr] = (__bf16)v;
          }
          *(bf16x4*)&pt[(nt * 16 + lm) * 72 + mt * 16 + q * 4] = w4;
        }
      }
      if (trk) {
#pragma unroll
        for (int d = 1; d < 64; d <<= 1) lmax = fmaxf(lmax, __shfl_xor(lmax, d));
        rpend = ilogbf(lmax);
      }
    }
  }

  // dump (bf16, exact copy of pt values): cb[it*512 + l*8 + e] = P[it*8+e][l]
  // 16 B/lane stores, 1 KiB/instruction, fully coalesced.
  __bf16* cb = chunks + (size_t)chunk * 4096;
#pragma unroll
  for (int it = 0; it < 8; ++it) {
    bf16x8 v;
#pragma unroll
    for (int e = 0; e < 8; ++e) v[e] = pt[(it * 8 + e) * 72 + l];
    *(bf16x8*)&cb[it * 512 + l * 8] = v;
  }
  if (l == 0) cexp[chunk] = (float)eacc;
}

// ---- combine: 64 blocks x 1 wave; 4-deep prefetch matvec chain (32 chunks) ----
__global__ __launch_bounds__(64) void k_combine(const __bf16* __restrict__ chunks,
                                                const float* __restrict__ cexp,
                                                const float* __restrict__ trans,
                                                const float* __restrict__ masks,
                                                const int* __restrict__ tags,
                                                const float* __restrict__ gold,
                                                float* __restrict__ out) {
  const int b = blockIdx.x;
  const int l = threadIdx.x;   // 0..63 = state i (column of P)
  __shared__ __align__(16) float vsh[64];
  float v = (l == S_START) ? 1.0f : 0.0f;
  float esum = 0.0f;
  const float LN2 = 0.6931471805599453f;

  float msum = 0.0f;
  for (int t = l; t < TT; t += 64) msum += masks[b * TT + t];

  const __bf16* base = chunks + ((size_t)(b * NCH)) * 4096;

  // 4-deep register prefetch: pf[p][it] holds rows it*8..it*8+7 of column l.
  bf16x8 pf[4][8];
#pragma unroll
  for (int p = 0; p < 4; ++p)
#pragma unroll
    for (int it = 0; it < 8; ++it)
      pf[p][it] = *(const bf16x8*)&base[(size_t)p * 4096 + it * 512 + l * 8];

#pragma unroll
  for (int cc = 0; cc < NCH; ++cc) {
    vsh[l] = v;
    __syncthreads();
    float u = 0.0f;
#pragma unroll
    for (int it = 0; it < 8; ++it) {
      bf16x8 m8 = pf[cc & 3][it];
      f32x4 va = *(const f32x4*)&vsh[it * 8];
      f32x4 vb = *(const f32x4*)&vsh[it * 8 + 4];
      u += (float)m8[0] * va[0] + (float)m8[1] * va[1]
         + (float)m8[2] * va[2] + (float)m8[3] * va[3]
         + (float)m8[4] * vb[0] + (float)m8[5] * vb[1]
         + (float)m8[6] * vb[2] + (float)m8[7] * vb[3];
    }
    // issue prefetch for cc+4 into the slot just consumed (regs force ordering)
    if (cc + 4 < NCH) {
#pragma unroll
      for (int it = 0; it < 8; ++it)
        pf[cc & 3][it] = *(const bf16x8*)&base[(size_t)(cc + 4) * 4096 + it * 512 + l * 8];
    }
    esum += cexp[b * NCH + cc] * LN2;
    float mxx = u;
#pragma unroll
    for (int d = 1; d < 64; d <<= 1) mxx = fmaxf(mxx, __shfl_xor(mxx, d));
    if (mxx > 0.0f) {
      int ee = ilogbf(mxx);
      u = ldexpf(u, -ee);
      esum += (float)ee * LN2;
    }
    v = u;
    __syncthreads();
  }

  float ts = (l < HH) ? trans[S_STOP * HH + l] : NEGV;  // exp(NEG)=0 excludes pads
  float contrib = v * __expf(ts);
#pragma unroll
  for (int d = 1; d < 64; d <<= 1) {
    contrib += __shfl_xor(contrib, d);
    msum += __shfl_xor(msum, d);
  }
  if (l == 0) {
    int lp = (int)(msum + 0.5f);
    int lt = (lp == 0) ? S_START : tags[b * TT + lp - 1];
    float goldb = gold[b] + trans[S_STOP * HH + lt];
    float fwd = __logf(contrib) + esum;
    atomicAdd(out, (fwd - goldb) * (1.0f / 64.0f));
  }
}

extern "C" void kernel_launch(void* const* d_in, const int* in_sizes, int n_in,
                              void* d_out, int out_size, void* d_ws, size_t ws_size,
                              hipStream_t stream) {
  (void)in_sizes; (void)n_in; (void)out_size; (void)ws_size;
  const float* feat  = (const float*)d_in[0];
  const float* W     = (const float*)d_in[1];
  const float* bias  = (const float*)d_in[2];
  const float* trans = (const float*)d_in[3];
  const float* masks = (const float*)d_in[4];
  const int*   tags  = (const int*)d_in[5];

  char* ws = (char*)d_ws;
  __bf16* chunks = (__bf16*)(ws + WS_CHUNK);
  __bf16* wbf    = (__bf16*)(ws + WS_WBF);
  __bf16* expT   = (__bf16*)(ws + WS_EXPT);
  float*  gold   = (float*)(ws + WS_GOLD);
  float*  cexp   = (float*)(ws + WS_CEXP);

  hipMemsetAsync(d_out, 0, sizeof(float), stream);
  k_prep<<<HP, 256, 0, stream>>>(W, trans, wbf, expT, gold);
  k_scan<<<(BB * NCH) / 4, 256, 0, stream>>>(feat, wbf, expT, bias, trans, masks,
                                             tags, chunks, cexp, gold);
  k_combine<<<BB, 64, 0, stream>>>(chunks, cexp, trans, masks, tags, gold, (float*)d_out);
}

// Round 3
// 268.620 us; speedup vs baseline: 1.0021x; 1.0021x over previous
//
#include <hip/hip_runtime.h>
#include <hip/hip_bf16.h>
#include <math.h>

// CRF loss on MI355X — 2-waves-per-chunk version (R5).
//   k_prep:    W fp32->bf16 (pad 52->64), expT = exp(Tpad) bf16 [64][64], zero gold
//   k_scan:    2 waves per chunk:
//                GEMM K-split (each wave K=512 half, partials summed via LDS,
//                2 block barriers) -> shared bf16 emit tile
//                scan column-split (wave h owns P columns [32h,32h+32) =
//                disjoint pt storage rows -> NO barriers in scan)
//              1024 blocks x 4 waves = 2 chunks/block; LDS 22.5KB -> 4 blocks/CU
//              = 16 waves/CU resident (2x the old TLP; old k_scan was 92% stalled)
//   k_combine: 32 sequential 64x64 matvecs per batch, 4-deep register prefetch;
//              per-column-half exponents absorbed exactly via ldexpf on vsh.
//
// Scan math: P <- diag(exp(emit_t - (7+r)ln2)) * exp(Tpad) * P; per-half integer
// exponent eacc (cexp2[chunk*2+h]); rescale decision at t==7 from own-half max
// (halves may differ by a few powers of 2 -> combined exactly in k_combine).
// Padding: Tpad[i][j>=52]=NEG (exp->0), Tpad[i>=52][j<52]=0.

#define NEGV   (-100000000.0f)
#define BB     64
#define TT     512
#define FF     1024
#define HH     52
#define HP     64
#define S_START 50
#define S_STOP  51
#define NCH    32            // chunks per batch
#define CLEN   (TT / NCH)    // 16 steps per chunk

typedef __bf16 bf16x8 __attribute__((ext_vector_type(8)));
typedef __bf16 bf16x4 __attribute__((ext_vector_type(4)));
typedef float  f32x4  __attribute__((ext_vector_type(4)));

// ---------------- ws layout (bytes) ----------------
#define WS_CHUNK  0u           // bf16 [2048][4096]               16,777,216
#define WS_CEXP2  16777216u    // fp32 [4096]                         16,384
#define WS_WBF    16793600u    // bf16 [HP][FF]                      131,072
#define WS_EXPT   16924672u    // bf16 [64][64]                        8,192
#define WS_GOLD   16932864u    // fp32 [BB]                              256

// ---- W fp32 -> bf16 (pad rows 52..63 = 0); block 0: gold=0 and expT ----
__global__ __launch_bounds__(256) void k_prep(const float* __restrict__ W,
                                              const float* __restrict__ trans,
                                              __bf16* __restrict__ wbf,
                                              __bf16* __restrict__ expT,
                                              float* __restrict__ gold) {
  int n = blockIdx.x;  // 0..63
  if (n == 0) {
    if (threadIdx.x < BB) gold[threadIdx.x] = 0.0f;
    for (int idx = threadIdx.x; idx < 4096; idx += 256) {
      int m = idx >> 6, k = idx & 63;
      float tv = (k >= HH) ? NEGV : ((m >= HH) ? 0.0f : trans[m * HH + k]);
      expT[idx] = (__bf16)__expf(tv);
    }
  }
  for (int k = threadIdx.x; k < FF; k += 256) {
    float v = (n < HH) ? W[n * FF + k] : 0.0f;
    wbf[n * FF + k] = (__bf16)v;
  }
}

// ---- fused GEMM + gold + scan: 1024 blocks x 4 waves; 2 waves per chunk ----
__global__ __launch_bounds__(256, 4) void k_scan(const float* __restrict__ feat,
                                                 const __bf16* __restrict__ wbf,
                                                 const __bf16* __restrict__ expT,
                                                 const float* __restrict__ bias,
                                                 const float* __restrict__ trans,
                                                 const float* __restrict__ masks,
                                                 const int* __restrict__ tags,
                                                 __bf16* __restrict__ chunks,
                                                 float* __restrict__ cexp2,
                                                 float* __restrict__ gold) {
  const int tid = threadIdx.x;
  const int wv = tid >> 6;
  const int l  = tid & 63;
  const int lm = l & 15;
  const int q  = l >> 4;
  const int ck = wv >> 1;        // chunk within block (0,1)
  const int h  = wv & 1;         // K-half in GEMM / column-half in scan
  const int chunk = blockIdx.x * 2 + ck;   // 0..2047
  const int b = chunk >> 5, c = chunk & 31;

  __shared__ __align__(16) __bf16 PTall[2][64 * 72];   // 18,432 B
  __shared__ __align__(16) __bf16 Eall[2][CLEN * 64];  //  4,096 B
  __bf16* pt = PTall[ck];
  __bf16* el = Eall[ck];
  float*  pstage = (float*)pt;   // reuse PT region for fp32 GEMM partials

  // ============ emit GEMM: M=16 (t), N=64 (state), K=512 half ============
  const float* fbase = feat + ((size_t)(b * TT + c * CLEN)) * FF;
  const float* arow  = fbase + (size_t)lm * FF + h * 512 + q * 8;

  // A prefetch, 4 k-chunks deep (32 B/lane per k-chunk)
  f32x4 apre[4][2];
#pragma unroll
  for (int s = 0; s < 4; ++s)
#pragma unroll
    for (int hh = 0; hh < 2; ++hh)
      apre[s][hh] = *(const f32x4*)(arow + s * 32 + hh * 4);

  bf16x8 bcur[4];
#pragma unroll
  for (int nt = 0; nt < 4; ++nt)
    bcur[nt] = *(const bf16x8*)(wbf + (size_t)(nt * 16 + lm) * FF + h * 512 + q * 8);

  f32x4 acc[4] = {};

#pragma unroll
  for (int kt = 0; kt < 16; ++kt) {
    const int st = kt & 3;
    bf16x8 af;
#pragma unroll
    for (int j = 0; j < 4; ++j) {
      af[j]     = (__bf16)apre[st][0][j];
      af[4 + j] = (__bf16)apre[st][1][j];
    }
    if (kt + 4 < 16) {
#pragma unroll
      for (int hh = 0; hh < 2; ++hh)
        apre[st][hh] = *(const f32x4*)(arow + (kt + 4) * 32 + hh * 4);
    }
    bf16x8 bnx[4];
    if (kt + 1 < 16) {
#pragma unroll
      for (int nt = 0; nt < 4; ++nt)
        bnx[nt] = *(const bf16x8*)(wbf + (size_t)(nt * 16 + lm) * FF + h * 512 + (kt + 1) * 32 + q * 8);
    }
#pragma unroll
    for (int nt = 0; nt < 4; ++nt)
      acc[nt] = __builtin_amdgcn_mfma_f32_16x16x32_bf16(af, bcur[nt], acc[nt], 0, 0, 0);
    if (kt + 1 < 16) {
#pragma unroll
      for (int nt = 0; nt < 4; ++nt) bcur[nt] = bnx[nt];
    }
  }

  // stage fp32 partial: pstage[h*1024 + row*64 + n]; D: row=q*4+rr, col=lm
#pragma unroll
  for (int nt = 0; nt < 4; ++nt)
#pragma unroll
    for (int rr = 0; rr < 4; ++rr)
      pstage[h * 1024 + (q * 4 + rr) * 64 + nt * 16 + lm] = acc[nt][rr];
  __syncthreads();

  // build el: wave h sums both halves for rows t = 2*i2 + h
  {
    float bl = (l < HH) ? bias[l] : 0.0f;
#pragma unroll
    for (int i2 = 0; i2 < 8; ++i2) {
      int t = i2 * 2 + h;
      el[t * 64 + l] = (__bf16)(pstage[t * 64 + l] + pstage[1024 + t * 64 + l] + bl);
    }
  }
  __syncthreads();   // el ready everywhere; pstage readers done -> pt reusable

  // ================= gold partial (wave h==0 of each chunk) =================
  float mreg = (l < CLEN) ? masks[b * TT + c * CLEN + l] : 1.0f;
  if (h == 0) {
    int cur = (l < CLEN) ? tags[b * TT + c * CLEN + l] : 0;
    int prev = __shfl_up(cur, 1);
    if (l == 0) prev = (c == 0) ? S_START : tags[b * TT + c * CLEN - 1];
    float gp = 0.0f;
    if (l < CLEN) {
      float e  = (float)el[l * 64 + cur];
      float tr = trans[cur * HH + prev];
      gp = (e + tr) * mreg;
    }
#pragma unroll
    for (int d = 1; d < 64; d <<= 1) gp += __shfl_xor(gp, d);
    if (l == 0) atomicAdd(&gold[b], gp);
  }

  // ================= scan (column-split, no barriers) =================
  // constant A = exp(Tpad): full rows per wave
  bf16x8 afrag[4][2];
#pragma unroll
  for (int mt = 0; mt < 4; ++mt)
#pragma unroll
    for (int kk = 0; kk < 2; ++kk)
      afrag[mt][kk] = *(const bf16x8*)&expT[(mt * 16 + lm) * 64 + kk * 32 + q * 8];

  // P = I on own storage rows j in [32h, 32h+32)
#pragma unroll
  for (int r = 0; r < 32; ++r) {
    int j = h * 32 + r;
    pt[j * 72 + l] = (__bf16)((j == l) ? 1.0f : 0.0f);
  }

  int eacc = 0, rpend = 0;
  const float LOG2E = 1.4426950408889634f;

  for (int t = 0; t < CLEN; ++t) {
    float mcur = __shfl(mreg, t);             // wave-uniform
    if (mcur != 0.0f) {
      float sh = (float)(7 + rpend);
      eacc += 7 + rpend;
      rpend = 0;
      float s[4][4];
#pragma unroll
      for (int mt = 0; mt < 4; ++mt) {
        bf16x4 em4 = *(const bf16x4*)&el[t * 64 + mt * 16 + q * 4];
#pragma unroll
        for (int rr = 0; rr < 4; ++rr)
          s[mt][rr] = __builtin_amdgcn_exp2f(fmaf((float)em4[rr], LOG2E, -sh));
      }

      // own-half reads (in-order LDS per wave; disjoint rows across waves)
      bf16x8 bfr[2][2];
#pragma unroll
      for (int kk = 0; kk < 2; ++kk)
#pragma unroll
        for (int nt = 0; nt < 2; ++nt)
          bfr[kk][nt] = *(const bf16x8*)&pt[((h * 2 + nt) * 16 + lm) * 72 + kk * 32 + q * 8];

      const bool trk = (t == 7);
      float lmax = 0.0f;
      f32x4 zero = {};
#pragma unroll
      for (int mt = 0; mt < 4; ++mt) {
#pragma unroll
        for (int nt = 0; nt < 2; ++nt) {
          f32x4 a = __builtin_amdgcn_mfma_f32_16x16x32_bf16(afrag[mt][0], bfr[0][nt], zero, 0, 0, 0);
          a = __builtin_amdgcn_mfma_f32_16x16x32_bf16(afrag[mt][1], bfr[1][nt], a, 0, 0, 0);
          bf16x4 w4;
#pragma unroll
          for (int rr = 0; rr < 4; ++rr) {
            float v = a[rr] * s[mt][rr];
            if (trk) lmax = fmaxf(lmax, v);
            w4[rr] = (__bf16)v;
          }
          *(bf16x4*)&pt[((h * 2 + nt) * 16 + lm) * 72 + mt * 16 + q * 4] = w4;
        }
      }
      if (trk) {
#pragma unroll
        for (int d = 1; d < 64; d <<= 1) lmax = fmaxf(lmax, __shfl_xor(lmax, d));
        if (lmax > 0.0f) rpend = ilogbf(lmax);
      }
    }
  }

  // dump own columns j in [32h,32h+32): cb[it*512 + l*8 + e] = P[i=l][j=it*8+e]
  __bf16* cb = chunks + (size_t)chunk * 4096;
#pragma unroll
  for (int i4 = 0; i4 < 4; ++i4) {
    int it = h * 4 + i4;
    bf16x8 v;
#pragma unroll
    for (int e = 0; e < 8; ++e) v[e] = pt[(it * 8 + e) * 72 + l];
    *(bf16x8*)&cb[it * 512 + l * 8] = v;
  }
  if (l == 0) cexp2[chunk * 2 + h] = (float)eacc;
}

// ---- combine: 64 blocks x 1 wave; 4-deep prefetch matvec chain (32 chunks) ----
__global__ __launch_bounds__(64) void k_combine(const __bf16* __restrict__ chunks,
                                                const float* __restrict__ cexp2,
                                                const float* __restrict__ trans,
                                                const float* __restrict__ masks,
                                                const int* __restrict__ tags,
                                                const float* __restrict__ gold,
                                                float* __restrict__ out) {
  const int b = blockIdx.x;
  const int l = threadIdx.x;   // 0..63 = state i (row of M = output index)
  __shared__ __align__(16) float vsh[64];
  float v = (l == S_START) ? 1.0f : 0.0f;
  float esum = 0.0f;
  const float LN2 = 0.6931471805599453f;

  float msum = 0.0f;
  for (int t = l; t < TT; t += 64) msum += masks[b * TT + t];

  const __bf16* base = chunks + ((size_t)(b * NCH)) * 4096;

  // 4-deep register prefetch: pf[p][it] holds cols it*8..it*8+7 of row l.
  bf16x8 pf[4][8];
#pragma unroll
  for (int p = 0; p < 4; ++p)
#pragma unroll
    for (int it = 0; it < 8; ++it)
      pf[p][it] = *(const bf16x8*)&base[(size_t)p * 4096 + it * 512 + l * 8];

#pragma unroll
  for (int cc = 0; cc < NCH; ++cc) {
    // per-column-half exponents of this link, absorbed exactly into vsh
    float E0 = cexp2[(b * NCH + cc) * 2];
    float E1 = cexp2[(b * NCH + cc) * 2 + 1];
    float Em = fmaxf(E0, E1);
    int   dl = (int)(((l < 32) ? E0 : E1) - Em);
    vsh[l] = ldexpf(v, dl);
    __syncthreads();
    float u = 0.0f;
#pragma unroll
    for (int it = 0; it < 8; ++it) {
      bf16x8 m8 = pf[cc & 3][it];
      f32x4 va = *(const f32x4*)&vsh[it * 8];
      f32x4 vb = *(const f32x4*)&vsh[it * 8 + 4];
      u += (float)m8[0] * va[0] + (float)m8[1] * va[1]
         + (float)m8[2] * va[2] + (float)m8[3] * va[3]
         + (float)m8[4] * vb[0] + (float)m8[5] * vb[1]
         + (float)m8[6] * vb[2] + (float)m8[7] * vb[3];
    }
    // issue prefetch for cc+4 into the slot just consumed
    if (cc + 4 < NCH) {
#pragma unroll
      for (int it = 0; it < 8; ++it)
        pf[cc & 3][it] = *(const bf16x8*)&base[(size_t)(cc + 4) * 4096 + it * 512 + l * 8];
    }
    esum += Em * LN2;
    float mxx = u;
#pragma unroll
    for (int d = 1; d < 64; d <<= 1) mxx = fmaxf(mxx, __shfl_xor(mxx, d));
    if (mxx > 0.0f) {
      int ee = ilogbf(mxx);
      u = ldexpf(u, -ee);
      esum += (float)ee * LN2;
    }
    v = u;
    __syncthreads();
  }

  float ts = (l < HH) ? trans[S_STOP * HH + l] : NEGV;  // exp(NEG)=0 excludes pads
  float contrib = v * __expf(ts);
#pragma unroll
  for (int d = 1; d < 64; d <<= 1) {
    contrib += __shfl_xor(contrib, d);
    msum += __shfl_xor(msum, d);
  }
  if (l == 0) {
    int lp = (int)(msum + 0.5f);
    int lt = (lp == 0) ? S_START : tags[b * TT + lp - 1];
    float goldb = gold[b] + trans[S_STOP * HH + lt];
    float fwd = __logf(contrib) + esum;
    atomicAdd(out, (fwd - goldb) * (1.0f / 64.0f));
  }
}

extern "C" void kernel_launch(void* const* d_in, const int* in_sizes, int n_in,
                              void* d_out, int out_size, void* d_ws, size_t ws_size,
                              hipStream_t stream) {
  (void)in_sizes; (void)n_in; (void)out_size; (void)ws_size;
  const float* feat  = (const float*)d_in[0];
  const float* W     = (const float*)d_in[1];
  const float* bias  = (const float*)d_in[2];
  const float* trans = (const float*)d_in[3];
  const float* masks = (const float*)d_in[4];
  const int*   tags  = (const int*)d_in[5];

  char* ws = (char*)d_ws;
  __bf16* chunks = (__bf16*)(ws + WS_CHUNK);
  float*  cexp2  = (float*)(ws + WS_CEXP2);
  __bf16* wbf    = (__bf16*)(ws + WS_WBF);
  __bf16* expT   = (__bf16*)(ws + WS_EXPT);
  float*  gold   = (float*)(ws + WS_GOLD);

  hipMemsetAsync(d_out, 0, sizeof(float), stream);
  k_prep<<<HP, 256, 0, stream>>>(W, trans, wbf, expT, gold);
  k_scan<<<(BB * NCH) / 2, 256, 0, stream>>>(feat, wbf, expT, bias, trans, masks,
                                             tags, chunks, cexp2, gold);
  k_combine<<<BB, 64, 0, stream>>>(chunks, cexp2, trans, masks, tags, gold, (float*)d_out);
}